// Round 2
// 612.105 us; speedup vs baseline: 1.0324x; 1.0324x over previous
//
#include <hip/hip_runtime.h>
#include <math.h>

#define R_ROIS 2000
#define NOBJ   21
#define NACT   27
#define HUMAN  14
#define CFEAT  512
#define HF     38
#define WF     50
#define DFEAT  (CFEAT*7*7)   // 25088
#define H1DIM  4096

typedef float floatx4 __attribute__((ext_vector_type(4)));

// ---- ws layout (float offsets) ----
#define WS_KEPT   0                  // 20*4 boxes (feature coords, yxyx), label-indexed
#define WS_FEAT   80                 // 25088
#define WS_H1     (WS_FEAT + DFEAT)  // 4096 (pre-bias accumulator)
#define WS_FC7    (WS_H1 + H1DIM)    // 4096 (pre-bias accumulator)
#define WS_LOC    (WS_FC7 + H1DIM)   // 4
#define WS_ACT    (WS_LOC + 4)       // 27

// Fused: per-class top-box selection (NMS with thresh 0.0 keeps exactly the
// top-prob box per class), with per-row logZ recomputed on the fly, plus
// zero-init of the matvec accumulators (ws is poisoned 0xAA each call).
// One block per class channel 1..20.
__global__ __launch_bounds__(256)
void k_top(const float* __restrict__ scores, const float* __restrict__ off,
           const float* __restrict__ rois, const int* __restrict__ imgshape,
           float* __restrict__ kept_box, float* __restrict__ h1,
           float* __restrict__ fc7) {
    // cooperative zero of h1[4096] + fc7[4096] across the 20*256 threads
    int g = blockIdx.x * 256 + threadIdx.x;
    for (int j = g; j < 2 * H1DIM; j += 20 * 256) {
        if (j < H1DIM) h1[j] = 0.f; else fc7[j - H1DIM] = 0.f;
    }

    int cls = blockIdx.x + 1;  // class channel 1..20 -> label cls-1
    __shared__ float sval[256];
    __shared__ int   sidx[256];
    float best = -1e30f; int bidx = 0x7fffffff;
    for (int r = threadIdx.x; r < R_ROIS; r += 256) {
        const float* s = scores + r * NOBJ;
        float m = s[0];
        #pragma unroll
        for (int c = 1; c < NOBJ; ++c) m = fmaxf(m, s[c]);
        float sum = 0.f;
        #pragma unroll
        for (int c = 0; c < NOBJ; ++c) sum += expf(s[c] - m);
        float v = s[cls] - (m + logf(sum));   // same association as split version
        if (v > best) { best = v; bidx = r; }
    }
    sval[threadIdx.x] = best; sidx[threadIdx.x] = bidx;
    __syncthreads();
    for (int s = 128; s > 0; s >>= 1) {
        if (threadIdx.x < s) {
            float ov = sval[threadIdx.x + s]; int oi = sidx[threadIdx.x + s];
            if (ov > sval[threadIdx.x] ||
                (ov == sval[threadIdx.x] && oi < sidx[threadIdx.x])) {
                sval[threadIdx.x] = ov; sidx[threadIdx.x] = oi;
            }
        }
        __syncthreads();
    }
    if (threadIdx.x == 0) {
        int r = sidx[0];
        float Himg = (float)imgshape[0], Wimg = (float)imgshape[1];
        float sy = (float)HF / Himg, sx = (float)WF / Wimg;
        float y1 = rois[r*4+0]*sy, x1 = rois[r*4+1]*sx;
        float y2 = rois[r*4+2]*sy, x2 = rois[r*4+3]*sx;
        float dy = off[r*(NOBJ*4) + cls*4+0] * 0.1f;
        float dx = off[r*(NOBJ*4) + cls*4+1] * 0.1f;
        float dh = off[r*(NOBJ*4) + cls*4+2] * 0.2f;
        float dw = off[r*(NOBJ*4) + cls*4+3] * 0.2f;
        float h = y2 - y1, w = x2 - x1;
        float cy = y1 + 0.5f*h, cx = x1 + 0.5f*w;
        float cy2 = dy*h + cy, cx2 = dx*w + cx;
        float h2 = expf(dh)*h, w2 = expf(dw)*w;
        float by1 = fminf(fmaxf(cy2 - 0.5f*h2, 0.f), (float)HF);
        float bx1 = fminf(fmaxf(cx2 - 0.5f*w2, 0.f), (float)WF);
        float by2 = fminf(fmaxf(cy2 + 0.5f*h2, 0.f), (float)HF);
        float bx2 = fminf(fmaxf(cx2 + 0.5f*w2, 0.f), (float)WF);
        int l = cls - 1;
        kept_box[l*4+0] = by1; kept_box[l*4+1] = bx1;
        kept_box[l*4+2] = by2; kept_box[l*4+3] = bx2;
    }
}

// chainer RoIPooling2D on the human box (feature coords, scaled AGAIN by 1/16 — quirk preserved)
__global__ void k_roipool(const float* __restrict__ x, const float* __restrict__ kept_box,
                          float* __restrict__ feat) {
    int idx = blockIdx.x * blockDim.x + threadIdx.x;
    if (idx >= DFEAT) return;
    float y1 = kept_box[HUMAN*4+0], x1 = kept_box[HUMAN*4+1];
    float y2 = kept_box[HUMAN*4+2], x2 = kept_box[HUMAN*4+3];
    // jnp.round = round-half-to-even = rintf
    int xmin = (int)rintf(x1 * 0.0625f);
    int ymin = (int)rintf(y1 * 0.0625f);
    int xmax = (int)rintf(x2 * 0.0625f);
    int ymax = (int)rintf(y2 * 0.0625f);
    float rw = (float)max(xmax - xmin + 1, 1);
    float rh = (float)max(ymax - ymin + 1, 1);
    int c = idx / 49, rem = idx % 49, pi = rem / 7, pj = rem % 7;
    int hs  = min(max(ymin + (int)floorf((float)pi * rh / 7.f), 0), HF);
    int he  = min(max(ymin + (int)ceilf((float)(pi+1) * rh / 7.f), 0), HF);
    int wss = min(max(xmin + (int)floorf((float)pj * rw / 7.f), 0), WF);
    int we  = min(max(xmin + (int)ceilf((float)(pj+1) * rw / 7.f), 0), WF);
    float m = -1e30f;
    for (int rr = hs; rr < he; ++rr)
        for (int cc = wss; cc < we; ++cc)
            m = fmaxf(m, x[c*(HF*WF) + rr*WF + cc]);
    feat[idx] = (m <= -5e29f) ? 0.f : m;
}

// v^T @ W matvec, W row-major [nrows, ncols]. grid.x = row chunks (ROWS each),
// grid.y = 1024-col tiles. Nontemporal float4 column loads (W is read-once —
// keep it out of L2 so the atomic accumulators stay resident).
// RELU: fuse bias+relu into the staging read of vin (vin is the pre-bias acc).
template<int ROWS, bool RELU>
__global__ __launch_bounds__(256)
void k_matvec(const float* __restrict__ W, const float* __restrict__ vin,
              const float* __restrict__ bias, float* __restrict__ vout, int ncols) {
    __shared__ float sv[ROWS];
    int row0 = blockIdx.x * ROWS;
    int col0 = blockIdx.y * 1024 + threadIdx.x * 4;
    for (int i = threadIdx.x; i < ROWS; i += 256) {
        float v = vin[row0 + i];
        if (RELU) v = fmaxf(v + bias[row0 + i], 0.f);
        sv[i] = v;
    }
    __syncthreads();
    float a0 = 0.f, a1 = 0.f, a2 = 0.f, a3 = 0.f;
    const floatx4* Wv = (const floatx4*)W;
    long base = ((long)row0 * ncols + col0) >> 2;
    int stride = ncols >> 2;
    #pragma unroll 8
    for (int i = 0; i < ROWS; ++i) {
        float f = sv[i];
        floatx4 w = __builtin_nontemporal_load(&Wv[base + (long)i * stride]);
        a0 += f * w.x; a1 += f * w.y; a2 += f * w.z; a3 += f * w.w;
    }
    atomicAdd(&vout[col0+0], a0);
    atomicAdd(&vout[col0+1], a1);
    atomicAdd(&vout[col0+2], a2);
    atomicAdd(&vout[col0+3], a3);
}

// final small heads: 31 blocks, block k -> dot(relu(fc7+b2), col k of W_loc/W_act) + bias
__global__ void k_heads(const float* __restrict__ fc7, const float* __restrict__ b2,
                        const float* __restrict__ W_loc, const float* __restrict__ b_loc,
                        const float* __restrict__ W_act, const float* __restrict__ b_act,
                        float* __restrict__ loc_out, float* __restrict__ act_out) {
    int k = blockIdx.x;  // 0..30
    __shared__ float red[256];
    float sum = 0.f;
    if (k < 4) {
        for (int i = threadIdx.x; i < H1DIM; i += 256) {
            float f = fmaxf(fc7[i] + b2[i], 0.f);
            sum += f * W_loc[i*4 + k];
        }
    } else {
        int j = k - 4;
        for (int i = threadIdx.x; i < H1DIM; i += 256) {
            float f = fmaxf(fc7[i] + b2[i], 0.f);
            sum += f * W_act[i*NACT + j];
        }
    }
    red[threadIdx.x] = sum; __syncthreads();
    for (int s = 128; s > 0; s >>= 1) {
        if (threadIdx.x < s) red[threadIdx.x] += red[threadIdx.x + s];
        __syncthreads();
    }
    if (threadIdx.x == 0) {
        if (k < 4) loc_out[k] = red[0] + b_loc[k];
        else       act_out[k-4] = red[0] + b_act[k-4];
    }
}

// gaussian object pick over the 19 kept non-human boxes + write all 36 outputs
__global__ void k_final(const float* __restrict__ kept_box, const float* __restrict__ loc_out,
                        const float* __restrict__ act_out, const int* __restrict__ imgshape,
                        float* __restrict__ out) {
    if (threadIdx.x != 0 || blockIdx.x != 0) return;
    float hb0 = kept_box[HUMAN*4+0], hb1 = kept_box[HUMAN*4+1];
    float hb2 = kept_box[HUMAN*4+2], hb3 = kept_box[HUMAN*4+3];
    float h4w = hb3 - hb1, h4h = hb2 - hb0;
    float h4x = 0.5f * h4w, h4y = 0.5f * h4h;
    float hw = fmaxf(h4w, 1e-3f), hh = fmaxf(h4h, 1e-3f);
    float l0 = loc_out[0], l1 = loc_out[1], l2 = loc_out[2], l3 = loc_out[3];
    float muw = l3 - l1, muh = l2 - l0;
    float mux = 0.5f * muw, muy = 0.5f * muh;
    float bestg = -2.f; int bl = 0;
    for (int l = 0; l < 20; ++l) {
        if (l == HUMAN) continue;
        float b0 = kept_box[l*4+0], b1 = kept_box[l*4+1];
        float b2 = kept_box[l*4+2], b3 = kept_box[l*4+3];
        float cw = fmaxf(b3 - b1, 1e-3f), ch = fmaxf(b2 - b0, 1e-3f);
        float c0 = 0.5f * (b3 - b1), c1 = 0.5f * (b2 - b0);
        float d0 = (c0 - h4x) / hw - mux;
        float d1 = (c1 - h4y) / hh - muy;
        float d2 = logf(cw / hw) - muw;
        float d3 = logf(ch / hh) - muh;
        float g = expf(-(d0*d0 + d1*d1 + d2*d2 + d3*d3) / (2.f * 0.3f * 0.3f));
        if (g > bestg) { bestg = g; bl = l; }  // ascending l == first-in-flatten-order tie-break
    }
    float Himg = (float)imgshape[0], Wimg = (float)imgshape[1];
    float iy = Himg / (float)HF, ix = Wimg / (float)WF;
    out[0] = hb0 * iy; out[1] = hb1 * ix; out[2] = hb2 * iy; out[3] = hb3 * ix;
    out[4] = kept_box[bl*4+0] * iy; out[5] = kept_box[bl*4+1] * ix;
    out[6] = kept_box[bl*4+2] * iy; out[7] = kept_box[bl*4+3] * ix;
    for (int j = 0; j < NACT; ++j) out[8+j] = act_out[j];
    out[35] = (float)HF / Himg;
}

extern "C" void kernel_launch(void* const* d_in, const int* in_sizes, int n_in,
                              void* d_out, int out_size, void* d_ws, size_t ws_size,
                              hipStream_t stream) {
    const float* x           = (const float*)d_in[0];
    const float* pred_scores = (const float*)d_in[1];
    const float* pred_off    = (const float*)d_in[2];
    const float* rois        = (const float*)d_in[3];
    const int*   imgshape    = (const int*)d_in[4];
    const float* W1          = (const float*)d_in[5];
    const float* b1          = (const float*)d_in[6];
    const float* W2          = (const float*)d_in[7];
    const float* b2          = (const float*)d_in[8];
    const float* W_loc       = (const float*)d_in[9];
    const float* b_loc       = (const float*)d_in[10];
    const float* W_act       = (const float*)d_in[11];
    const float* b_act       = (const float*)d_in[12];
    float* out = (float*)d_out;

    float* ws   = (float*)d_ws;
    float* kept = ws + WS_KEPT;
    float* feat = ws + WS_FEAT;
    float* h1   = ws + WS_H1;
    float* fc7  = ws + WS_FC7;
    float* loco = ws + WS_LOC;
    float* acto = ws + WS_ACT;

    // 1: per-class top box + zero accumulators (20 blocks)
    k_top<<<20, 256, 0, stream>>>(pred_scores, pred_off, rois, imgshape, kept, h1, fc7);
    // 2: RoI pool the human box
    k_roipool<<<(DFEAT + 255) / 256, 256, 0, stream>>>(x, kept, feat);
    // 3: feat[25088] @ W1[25088,4096] -> h1 (pre-bias): 196 row-chunks x 4 col-tiles
    k_matvec<128, false><<<dim3(196, 4), 256, 0, stream>>>(W1, feat, (const float*)nullptr, h1, H1DIM);
    // 4: relu(h1+b1)[4096] @ W2[4096,4096] -> fc7 (pre-bias), bias+relu fused into staging
    k_matvec<64, true><<<dim3(64, 4), 256, 0, stream>>>(W2, h1, b1, fc7, H1DIM);
    // 5: heads, relu(fc7+b2) fused
    k_heads<<<31, 256, 0, stream>>>(fc7, b2, W_loc, b_loc, W_act, b_act, loco, acto);
    // 6: final outputs
    k_final<<<1, 64, 0, stream>>>(kept, loco, acto, imgshape, out);
}